// Round 1
// baseline (632.314 us; speedup 1.0000x reference)
//
#include <hip/hip_runtime.h>
#include <math.h>

// Problem constants (from reference: EMBED=256, HEADS=8, LEVELS=1, POINTS=4, QUEUE=2, 200x200)
#define NQ    40000
#define EMB   256
#define NHEAD 8
#define HDIM  32
#define HB    200
#define WB    200
#define NCOL  192   // 128 off cols + 64 aw cols
#define K1K   512

// ---------------------------------------------------------------------------
// K1: raw1[q, 0:128] = q2 @ W_off + b_off ; raw1[q, 128:192] = q2 @ W_attn + b_attn
//     q2[q] = concat(value[0,q,:], query[q]+query_pos[q])   (512)
// Tiled GEMM: BM=64, BN=192 (full), BK=32; 256 thr, thread tile 4x12.
// ---------------------------------------------------------------------------
__global__ __launch_bounds__(256) void k1_offaw(
    const float* __restrict__ query, const float* __restrict__ query_pos,
    const float* __restrict__ value, const float* __restrict__ W_off,
    const float* __restrict__ b_off, const float* __restrict__ W_attn,
    const float* __restrict__ b_attn, float* __restrict__ raw1)
{
  __shared__ float As[64][36];   // [m][k], +4 pad keeps 16B alignment
  __shared__ float Bs[32][192];
  const int t = threadIdx.x;
  const int m0 = blockIdx.x * 64;
  const int tmi = t >> 4, tni = t & 15;
  const int mb = tmi * 4, nb = tni * 12;

  float acc[4][12];
  #pragma unroll
  for (int i = 0; i < 4; i++)
    #pragma unroll
    for (int j = 0; j < 12; j++) acc[i][j] = 0.f;

  for (int k0 = 0; k0 < K1K; k0 += 32) {
    // ---- stage A (64x32): 512 float4s, 2 per thread
    #pragma unroll
    for (int l = 0; l < 2; l++) {
      int e = t + l * 256;
      int m = e >> 3, kq = (e & 7) * 4;
      int kk = k0 + kq;
      float4 va;
      if (kk < 256) {
        va = *(const float4*)(value + (size_t)(m0 + m) * EMB + kk);
      } else {
        float4 a = *(const float4*)(query     + (size_t)(m0 + m) * EMB + (kk - 256));
        float4 b = *(const float4*)(query_pos + (size_t)(m0 + m) * EMB + (kk - 256));
        va = make_float4(a.x + b.x, a.y + b.y, a.z + b.z, a.w + b.w);
      }
      *(float4*)(&As[m][kq]) = va;
    }
    // ---- stage B (32x192): 1536 float4s, 6 per thread
    #pragma unroll
    for (int l = 0; l < 6; l++) {
      int e = t + l * 256;
      int k = e / 48, cq = (e % 48) * 4;
      int kk = k0 + k;
      float4 vb;
      if (cq < 128) vb = *(const float4*)(W_off  + (size_t)kk * 128 + cq);
      else          vb = *(const float4*)(W_attn + (size_t)kk * 64  + (cq - 128));
      *(float4*)(&Bs[k][cq]) = vb;
    }
    __syncthreads();
    #pragma unroll
    for (int k = 0; k < 32; k++) {
      float a[4];
      #pragma unroll
      for (int i = 0; i < 4; i++) a[i] = As[mb + i][k];
      float4 b0 = *(const float4*)(&Bs[k][nb]);
      float4 b1 = *(const float4*)(&Bs[k][nb + 4]);
      float4 b2 = *(const float4*)(&Bs[k][nb + 8]);
      float bl[12] = {b0.x, b0.y, b0.z, b0.w, b1.x, b1.y, b1.z, b1.w,
                      b2.x, b2.y, b2.z, b2.w};
      #pragma unroll
      for (int i = 0; i < 4; i++)
        #pragma unroll
        for (int j = 0; j < 12; j++) acc[i][j] += a[i] * bl[j];
    }
    __syncthreads();
  }
  // ---- epilogue: bias + store
  #pragma unroll
  for (int i = 0; i < 4; i++) {
    int row = m0 + mb + i;
    #pragma unroll
    for (int j = 0; j < 12; j += 4) {
      float4 r;
      float v0[4];
      #pragma unroll
      for (int u = 0; u < 4; u++) {
        int c = nb + j + u;
        float bs = (c < 128) ? b_off[c] : b_attn[c - 128];
        v0[u] = acc[i][j + u] + bs;
      }
      r.x = v0[0]; r.y = v0[1]; r.z = v0[2]; r.w = v0[3];
      *(float4*)(raw1 + (size_t)row * NCOL + nb + j) = r;
    }
  }
}

// ---------------------------------------------------------------------------
// Generic (M x 256) @ (256 x 256) + bias [+ residual] GEMM.
// BM=64, BN=128 (grid.y=2), BK=32; thread tile 4x8.
// ---------------------------------------------------------------------------
__global__ __launch_bounds__(256) void k_gemm_e256(
    const float* __restrict__ A, const float* __restrict__ Bm,
    const float* __restrict__ bias, const float* __restrict__ resid,
    float* __restrict__ C)
{
  __shared__ float As[64][36];
  __shared__ float Bs[32][128];
  const int t = threadIdx.x;
  const int m0 = blockIdx.x * 64;
  const int n0 = blockIdx.y * 128;
  const int tmi = t >> 4, tni = t & 15;
  const int mb = tmi * 4, nb = tni * 8;

  float acc[4][8];
  #pragma unroll
  for (int i = 0; i < 4; i++)
    #pragma unroll
    for (int j = 0; j < 8; j++) acc[i][j] = 0.f;

  for (int k0 = 0; k0 < 256; k0 += 32) {
    #pragma unroll
    for (int l = 0; l < 2; l++) {
      int e = t + l * 256;
      int m = e >> 3, kq = (e & 7) * 4;
      *(float4*)(&As[m][kq]) =
          *(const float4*)(A + (size_t)(m0 + m) * 256 + k0 + kq);
    }
    #pragma unroll
    for (int l = 0; l < 4; l++) {
      int e = t + l * 256;
      int k = e >> 5, cq = (e & 31) * 4;
      *(float4*)(&Bs[k][cq]) =
          *(const float4*)(Bm + (size_t)(k0 + k) * 256 + n0 + cq);
    }
    __syncthreads();
    #pragma unroll
    for (int k = 0; k < 32; k++) {
      float a[4];
      #pragma unroll
      for (int i = 0; i < 4; i++) a[i] = As[mb + i][k];
      float4 b0 = *(const float4*)(&Bs[k][nb]);
      float4 b1 = *(const float4*)(&Bs[k][nb + 4]);
      float bl[8] = {b0.x, b0.y, b0.z, b0.w, b1.x, b1.y, b1.z, b1.w};
      #pragma unroll
      for (int i = 0; i < 4; i++)
        #pragma unroll
        for (int j = 0; j < 8; j++) acc[i][j] += a[i] * bl[j];
    }
    __syncthreads();
  }
  #pragma unroll
  for (int i = 0; i < 4; i++) {
    int row = m0 + mb + i;
    #pragma unroll
    for (int j = 0; j < 8; j += 4) {
      int c = n0 + nb + j;
      float4 r;
      r.x = acc[i][j + 0] + bias[c + 0];
      r.y = acc[i][j + 1] + bias[c + 1];
      r.z = acc[i][j + 2] + bias[c + 2];
      r.w = acc[i][j + 3] + bias[c + 3];
      if (resid != nullptr) {
        const float4 q = *(const float4*)(resid + (size_t)row * 256 + c);
        r.x += q.x; r.y += q.y; r.z += q.z; r.w += q.w;
      }
      *(float4*)(C + (size_t)row * 256 + c) = r;
    }
  }
}

// ---------------------------------------------------------------------------
// K3: per-query deformable sampling + queue mean.
// Block = 1 query, 256 threads = (head, dim). Phase 1 (64 thr): softmax + loc.
// grid_sample(align_corners=False, zeros): px = ref_x*W + off_x - 0.5
// ---------------------------------------------------------------------------
__global__ __launch_bounds__(256) void k3_sample(
    const float* __restrict__ raw1, const float* __restrict__ refp,
    const float* __restrict__ v, float* __restrict__ msd)
{
  __shared__ float4 smp[64];   // (b,h,p) -> (px, py, w, -)
  const int q = blockIdx.x;
  const int t = threadIdx.x;

  if (t < 64) {
    const int b = t >> 5, h = (t >> 2) & 7, p = t & 3;
    const float* r = raw1 + (size_t)q * NCOL;
    float ox = r[h * 16 + b * 8 + p * 2 + 0];
    float oy = r[h * 16 + b * 8 + p * 2 + 1];
    float l0 = r[128 + h * 8 + b * 4 + 0];
    float l1 = r[128 + h * 8 + b * 4 + 1];
    float l2 = r[128 + h * 8 + b * 4 + 2];
    float l3 = r[128 + h * 8 + b * 4 + 3];
    float mx = fmaxf(fmaxf(l0, l1), fmaxf(l2, l3));
    float e0 = expf(l0 - mx), e1 = expf(l1 - mx);
    float e2 = expf(l2 - mx), e3 = expf(l3 - mx);
    float s = e0 + e1 + e2 + e3;
    float ep = (p == 0) ? e0 : (p == 1) ? e1 : (p == 2) ? e2 : e3;
    float w = ep / s;
    float rx = refp[((size_t)b * NQ + q) * 2 + 0];
    float ry = refp[((size_t)b * NQ + q) * 2 + 1];
    float px = rx * (float)WB + ox - 0.5f;
    float py = ry * (float)HB + oy - 0.5f;
    smp[t] = make_float4(px, py, w, 0.f);
  }
  __syncthreads();

  const int d = t & 31, h = t >> 5;
  float accq = 0.f;
  #pragma unroll
  for (int b = 0; b < 2; b++) {
    #pragma unroll
    for (int p = 0; p < 4; p++) {
      float4 s = smp[b * 32 + h * 4 + p];
      float px = s.x, py = s.y, w = s.z;
      float x0f = floorf(px), y0f = floorf(py);
      float lx = px - x0f, ly = py - y0f;
      int x0 = (int)x0f, y0 = (int)y0f;
      int x1 = x0 + 1, y1 = y0 + 1;

      int x0c = min(max(x0, 0), WB - 1), x1c = min(max(x1, 0), WB - 1);
      int y0c = min(max(y0, 0), HB - 1), y1c = min(max(y1, 0), HB - 1);
      float vx0 = ((unsigned)x0 < (unsigned)WB) ? 1.f : 0.f;
      float vx1 = ((unsigned)x1 < (unsigned)WB) ? 1.f : 0.f;
      float vy0 = ((unsigned)y0 < (unsigned)HB) ? 1.f : 0.f;
      float vy1 = ((unsigned)y1 < (unsigned)HB) ? 1.f : 0.f;

      const size_t base = ((size_t)b * NQ) * (NHEAD * HDIM) + (size_t)h * HDIM + d;
      float v00 = v[base + (size_t)(y0c * WB + x0c) * (NHEAD * HDIM)];
      float v10 = v[base + (size_t)(y0c * WB + x1c) * (NHEAD * HDIM)];
      float v01 = v[base + (size_t)(y1c * WB + x0c) * (NHEAD * HDIM)];
      float v11 = v[base + (size_t)(y1c * WB + x1c) * (NHEAD * HDIM)];

      float w00 = (1.f - lx) * (1.f - ly) * vx0 * vy0;
      float w10 = lx * (1.f - ly) * vx1 * vy0;
      float w01 = (1.f - lx) * ly * vx0 * vy1;
      float w11 = lx * ly * vx1 * vy1;

      accq += w * (w00 * v00 + w10 * v10 + w01 * v01 + w11 * v11);
    }
  }
  msd[(size_t)q * EMB + t] = 0.5f * accq;
}

// ---------------------------------------------------------------------------
extern "C" void kernel_launch(void* const* d_in, const int* in_sizes, int n_in,
                              void* d_out, int out_size, void* d_ws, size_t ws_size,
                              hipStream_t stream) {
  const float* query     = (const float*)d_in[0];
  const float* query_pos = (const float*)d_in[1];
  const float* value     = (const float*)d_in[2];
  const float* refp      = (const float*)d_in[3];
  // d_in[4]: spatial_shapes (int32) — constant [200,200], hard-coded.
  const float* W_off  = (const float*)d_in[5];
  const float* b_off  = (const float*)d_in[6];
  const float* W_attn = (const float*)d_in[7];
  const float* b_attn = (const float*)d_in[8];
  const float* W_val  = (const float*)d_in[9];
  const float* b_val  = (const float*)d_in[10];
  const float* W_out  = (const float*)d_in[11];
  const float* b_out  = (const float*)d_in[12];
  float* out = (float*)d_out;

  char* ws = (char*)d_ws;
  float* raw1 = (float*)ws;                               // 40000*192*4 = 30.72 MB
  float* v    = (float*)(ws + 30720000);                  // 80000*256*4 = 81.92 MB
  float* msd  = (float*)(ws + 30720000 + 81920000);       // 40000*256*4 = 40.96 MB

  hipLaunchKernelGGL(k1_offaw, dim3(625), dim3(256), 0, stream,
                     query, query_pos, value, W_off, b_off, W_attn, b_attn, raw1);
  hipLaunchKernelGGL(k_gemm_e256, dim3(1250, 2), dim3(256), 0, stream,
                     value, W_val, b_val, (const float*)nullptr, v);
  hipLaunchKernelGGL(k3_sample, dim3(NQ), dim3(256), 0, stream,
                     raw1, refp, v, msd);
  hipLaunchKernelGGL(k_gemm_e256, dim3(625, 2), dim3(256), 0, stream,
                     msd, W_out, b_out, query, out);
}

// Round 2
// 617.851 us; speedup vs baseline: 1.0234x; 1.0234x over previous
//
#include <hip/hip_runtime.h>
#include <math.h>

// Problem constants: EMBED=256, HEADS=8, LEVELS=1, POINTS=4, QUEUE=2, 200x200
#define NQ    40000
#define NQP   40064   // padded to multiple of 128 for GEMM tiles
#define EMB   256
#define NHEAD 8
#define HDIM  32
#define HB    200
#define WB    200
#define NCOL  192     // 128 off cols + 64 aw cols

typedef __attribute__((ext_vector_type(8))) __bf16 bf16x8;
typedef __attribute__((ext_vector_type(4))) float f32x4;

static __device__ __forceinline__ unsigned short f2bf(float f) {
  unsigned u = __float_as_uint(f);
  u = u + 0x7fffu + ((u >> 16) & 1u);   // round-to-nearest-even
  return (unsigned short)(u >> 16);
}
static __device__ __forceinline__ float bf2f(unsigned short s) {
  return __uint_as_float(((unsigned)s) << 16);
}

// ---------------------------------------------------------------------------
// convV: value (80000x256 fp32) -> vb bf16
// ---------------------------------------------------------------------------
__global__ __launch_bounds__(256) void conv_value(
    const float* __restrict__ value, unsigned short* __restrict__ vb)
{
  int idx = blockIdx.x * 256 + threadIdx.x;   // quad index, 5.12M total
  float4 v = *(const float4*)(value + (size_t)idx * 4);
  ushort4 o;
  o.x = f2bf(v.x); o.y = f2bf(v.y); o.z = f2bf(v.z); o.w = f2bf(v.w);
  *(ushort4*)(vb + (size_t)idx * 4) = o;
}

// ---------------------------------------------------------------------------
// convQ2: q2b[q, 0:256] = value[0,q,:], q2b[q, 256:512] = query[q]+query_pos[q]
// ---------------------------------------------------------------------------
__global__ __launch_bounds__(256) void conv_q2(
    const float* __restrict__ query, const float* __restrict__ query_pos,
    const float* __restrict__ value, unsigned short* __restrict__ q2b)
{
  int idx = blockIdx.x * 256 + threadIdx.x;   // 40000*128 quads
  int q = idx >> 7;
  int c4 = (idx & 127) * 4;
  float4 v;
  if (c4 < 256) {
    v = *(const float4*)(value + (size_t)q * EMB + c4);
  } else {
    float4 a = *(const float4*)(query     + (size_t)q * EMB + (c4 - 256));
    float4 b = *(const float4*)(query_pos + (size_t)q * EMB + (c4 - 256));
    v = make_float4(a.x + b.x, a.y + b.y, a.z + b.z, a.w + b.w);
  }
  ushort4 o;
  o.x = f2bf(v.x); o.y = f2bf(v.y); o.z = f2bf(v.z); o.w = f2bf(v.w);
  *(ushort4*)(q2b + (size_t)q * 512 + c4) = o;
}

// ---------------------------------------------------------------------------
// conv_w: transposed bf16 weights + combined bias
//  Wc1t [192][512]  (cols of [W_off | W_attn]),  Wvt [256][256],  Wot [256][256]
//  bc1[192] = [b_off | b_attn] fp32
// ---------------------------------------------------------------------------
__global__ __launch_bounds__(256) void conv_w(
    const float* __restrict__ W_off, const float* __restrict__ b_off,
    const float* __restrict__ W_attn, const float* __restrict__ b_attn,
    const float* __restrict__ W_val, const float* __restrict__ W_out,
    unsigned short* __restrict__ Wc1t, unsigned short* __restrict__ Wvt,
    unsigned short* __restrict__ Wot, float* __restrict__ bc1)
{
  int idx = blockIdx.x * 256 + threadIdx.x;
  if (idx < 98304) {                       // Wc1t: n=idx>>9, k=idx&511
    int n = idx >> 9, k = idx & 511;
    float v = (n < 128) ? W_off[(size_t)k * 128 + n] : W_attn[(size_t)k * 64 + (n - 128)];
    Wc1t[idx] = f2bf(v);
  } else if (idx < 163840) {               // Wvt
    int j = idx - 98304;
    int n = j >> 8, k = j & 255;
    Wvt[j] = f2bf(W_val[(size_t)k * 256 + n]);
  } else if (idx < 229376) {               // Wot
    int j = idx - 163840;
    int n = j >> 8, k = j & 255;
    Wot[j] = f2bf(W_out[(size_t)k * 256 + n]);
  } else if (idx < 229568) {               // bc1
    int n = idx - 229376;
    bc1[n] = (n < 128) ? b_off[n] : b_attn[n - 128];
  }
}

// ---------------------------------------------------------------------------
// MFMA bf16 GEMM: C[M x N] = A[M x K] @ Bt[N x K]^T + bias (+resid)
// BM=128, BN=64, BK=64; 256 thr = 4 waves (2x2), wave tile 64x32 = 4x2 frags
// of 16x16x32 MFMA. LDS padded (+8 ushort) -> frag ds_read_b128 is 2-way.
// ---------------------------------------------------------------------------
template<int K, int N, int MROWS, bool OUT_BF16, bool RESID>
__global__ __launch_bounds__(256) void mfma_gemm(
    const unsigned short* __restrict__ A, const unsigned short* __restrict__ Bt,
    const float* __restrict__ bias, const float* __restrict__ resid,
    void* __restrict__ outp)
{
  __shared__ unsigned short As[128][72];
  __shared__ unsigned short Bs[64][72];
  const int t = threadIdx.x;
  const int m0 = blockIdx.x * 128;
  const int n0 = blockIdx.y * 64;
  const int wid = t >> 6, lane = t & 63;
  const int wm = (wid >> 1) * 64, wn = (wid & 1) * 32;
  const int lr = lane & 15, quad = lane >> 4;

  f32x4 acc[4][2];
  #pragma unroll
  for (int i = 0; i < 4; i++)
    #pragma unroll
    for (int n = 0; n < 2; n++) acc[i][n] = (f32x4){0.f, 0.f, 0.f, 0.f};

  for (int k0 = 0; k0 < K; k0 += 64) {
    uint4 ra[4], rb[2];
    #pragma unroll
    for (int l = 0; l < 4; l++) {
      int e = t + l * 256; int m = e >> 3, kq = (e & 7) * 8;
      ra[l] = *(const uint4*)(A + (size_t)(m0 + m) * K + k0 + kq);
    }
    #pragma unroll
    for (int l = 0; l < 2; l++) {
      int e = t + l * 256; int n = e >> 3, kq = (e & 7) * 8;
      rb[l] = *(const uint4*)(Bt + (size_t)(n0 + n) * K + k0 + kq);
    }
    __syncthreads();   // previous iteration's LDS reads complete
    #pragma unroll
    for (int l = 0; l < 4; l++) {
      int e = t + l * 256; int m = e >> 3, kq = (e & 7) * 8;
      *(uint4*)(&As[m][kq]) = ra[l];
    }
    #pragma unroll
    for (int l = 0; l < 2; l++) {
      int e = t + l * 256; int n = e >> 3, kq = (e & 7) * 8;
      *(uint4*)(&Bs[n][kq]) = rb[l];
    }
    __syncthreads();
    #pragma unroll
    for (int kk = 0; kk < 64; kk += 32) {
      bf16x8 af[4], bf[2];
      #pragma unroll
      for (int i = 0; i < 4; i++)
        af[i] = *(const bf16x8*)(&As[wm + i * 16 + lr][kk + quad * 8]);
      #pragma unroll
      for (int n = 0; n < 2; n++)
        bf[n] = *(const bf16x8*)(&Bs[wn + n * 16 + lr][kk + quad * 8]);
      #pragma unroll
      for (int i = 0; i < 4; i++)
        #pragma unroll
        for (int n = 0; n < 2; n++)
          acc[i][n] = __builtin_amdgcn_mfma_f32_16x16x32_bf16(af[i], bf[n], acc[i][n], 0, 0, 0);
    }
  }

  // epilogue: C/D layout col=lane&15, row=quad*4+reg
  #pragma unroll
  for (int i = 0; i < 4; i++) {
    int rowb = m0 + wm + i * 16 + quad * 4;
    #pragma unroll
    for (int n = 0; n < 2; n++) {
      int col = n0 + wn + n * 16 + lr;
      float bsv = bias[col];
      #pragma unroll
      for (int r = 0; r < 4; r++) {
        int rr = rowb + r;
        if ((MROWS % 128 == 0) || rr < MROWS) {
          float v = acc[i][n][r] + bsv;
          if (RESID) v += resid[(size_t)rr * N + col];
          if (OUT_BF16) ((unsigned short*)outp)[(size_t)rr * N + col] = f2bf(v);
          else          ((float*)outp)[(size_t)rr * N + col] = v;
        }
      }
    }
  }
}

// ---------------------------------------------------------------------------
// K3: per-query deformable sampling + queue mean. v is bf16, msd out bf16.
// ---------------------------------------------------------------------------
__global__ __launch_bounds__(256) void k3_sample(
    const float* __restrict__ raw1, const float* __restrict__ refp,
    const unsigned short* __restrict__ v, unsigned short* __restrict__ msd)
{
  __shared__ float4 smp[64];   // (b,h,p) -> (px, py, w, -)
  const int q = blockIdx.x;
  const int t = threadIdx.x;

  if (t < 64) {
    const int b = t >> 5, h = (t >> 2) & 7, p = t & 3;
    const float* r = raw1 + (size_t)q * NCOL;
    float ox = r[h * 16 + b * 8 + p * 2 + 0];
    float oy = r[h * 16 + b * 8 + p * 2 + 1];
    float l0 = r[128 + h * 8 + b * 4 + 0];
    float l1 = r[128 + h * 8 + b * 4 + 1];
    float l2 = r[128 + h * 8 + b * 4 + 2];
    float l3 = r[128 + h * 8 + b * 4 + 3];
    float mx = fmaxf(fmaxf(l0, l1), fmaxf(l2, l3));
    float e0 = expf(l0 - mx), e1 = expf(l1 - mx);
    float e2 = expf(l2 - mx), e3 = expf(l3 - mx);
    float s = e0 + e1 + e2 + e3;
    float ep = (p == 0) ? e0 : (p == 1) ? e1 : (p == 2) ? e2 : e3;
    float w = ep / s;
    float rx = refp[((size_t)b * NQ + q) * 2 + 0];
    float ry = refp[((size_t)b * NQ + q) * 2 + 1];
    float px = rx * (float)WB + ox - 0.5f;
    float py = ry * (float)HB + oy - 0.5f;
    smp[t] = make_float4(px, py, w, 0.f);
  }
  __syncthreads();

  const int d = t & 31, h = t >> 5;
  float accq = 0.f;
  #pragma unroll
  for (int b = 0; b < 2; b++) {
    #pragma unroll
    for (int p = 0; p < 4; p++) {
      float4 s = smp[b * 32 + h * 4 + p];
      float px = s.x, py = s.y, w = s.z;
      float x0f = floorf(px), y0f = floorf(py);
      float lx = px - x0f, ly = py - y0f;
      int x0 = (int)x0f, y0 = (int)y0f;
      int x1 = x0 + 1, y1 = y0 + 1;

      int x0c = min(max(x0, 0), WB - 1), x1c = min(max(x1, 0), WB - 1);
      int y0c = min(max(y0, 0), HB - 1), y1c = min(max(y1, 0), HB - 1);
      float vx0 = ((unsigned)x0 < (unsigned)WB) ? 1.f : 0.f;
      float vx1 = ((unsigned)x1 < (unsigned)WB) ? 1.f : 0.f;
      float vy0 = ((unsigned)y0 < (unsigned)HB) ? 1.f : 0.f;
      float vy1 = ((unsigned)y1 < (unsigned)HB) ? 1.f : 0.f;

      const size_t base = ((size_t)b * NQ) * EMB + (size_t)h * HDIM + d;
      float v00 = bf2f(v[base + (size_t)(y0c * WB + x0c) * EMB]);
      float v10 = bf2f(v[base + (size_t)(y0c * WB + x1c) * EMB]);
      float v01 = bf2f(v[base + (size_t)(y1c * WB + x0c) * EMB]);
      float v11 = bf2f(v[base + (size_t)(y1c * WB + x1c) * EMB]);

      float w00 = (1.f - lx) * (1.f - ly) * vx0 * vy0;
      float w10 = lx * (1.f - ly) * vx1 * vy0;
      float w01 = (1.f - lx) * ly * vx0 * vy1;
      float w11 = lx * ly * vx1 * vy1;

      accq += w * (w00 * v00 + w10 * v10 + w01 * v01 + w11 * v11);
    }
  }
  msd[(size_t)q * EMB + t] = f2bf(0.5f * accq);
}

// ---------------------------------------------------------------------------
extern "C" void kernel_launch(void* const* d_in, const int* in_sizes, int n_in,
                              void* d_out, int out_size, void* d_ws, size_t ws_size,
                              hipStream_t stream) {
  const float* query     = (const float*)d_in[0];
  const float* query_pos = (const float*)d_in[1];
  const float* value     = (const float*)d_in[2];
  const float* refp      = (const float*)d_in[3];
  // d_in[4]: spatial_shapes constant [200,200]
  const float* W_off  = (const float*)d_in[5];
  const float* b_off  = (const float*)d_in[6];
  const float* W_attn = (const float*)d_in[7];
  const float* b_attn = (const float*)d_in[8];
  const float* W_val  = (const float*)d_in[9];
  const float* b_val  = (const float*)d_in[10];
  const float* W_out  = (const float*)d_in[11];
  const float* b_out  = (const float*)d_in[12];
  float* out = (float*)d_out;

  char* ws = (char*)d_ws;
  // buf0 (41,025,536 B): q2b [40064][512] bf16, later reused for v_out bf16
  unsigned short* q2b  = (unsigned short*)(ws);
  unsigned short* vout = (unsigned short*)(ws);            // reuse after k1
  unsigned short* vb   = (unsigned short*)(ws + 41025536); // 80000*256*2
  float*          raw1 = (float*)(ws + 81985536);          // 40000*192*4
  unsigned short* msdb = (unsigned short*)(ws + 112705536);// 40064*256*2
  unsigned short* Wc1t = (unsigned short*)(ws + 133218304);// 192*512*2
  unsigned short* Wvt  = (unsigned short*)(ws + 133414912);// 256*256*2
  unsigned short* Wot  = (unsigned short*)(ws + 133545984);// 256*256*2
  float*          bc1  = (float*)(ws + 133677056);         // 192*4

  hipLaunchKernelGGL(conv_w, dim3(897), dim3(256), 0, stream,
                     W_off, b_off, W_attn, b_attn, W_val, W_out, Wc1t, Wvt, Wot, bc1);
  hipLaunchKernelGGL(conv_value, dim3(20000), dim3(256), 0, stream, value, vb);
  hipLaunchKernelGGL(conv_q2, dim3(20000), dim3(256), 0, stream,
                     query, query_pos, value, q2b);

  // k1: raw1 = q2 @ [W_off|W_attn] + [b_off|b_attn]   (40000x512 @ 512x192)
  hipLaunchKernelGGL((mfma_gemm<512, 192, NQ, false, false>), dim3(313, 3), dim3(256), 0, stream,
                     q2b, Wc1t, bc1, (const float*)nullptr, raw1);
  // k2: v = value @ W_val + b_val  (80000x256 @ 256x256) -> bf16 (overwrites q2b region)
  hipLaunchKernelGGL((mfma_gemm<256, 256, 80000, true, false>), dim3(625, 4), dim3(256), 0, stream,
                     vb, Wvt, b_val, (const float*)nullptr, vout);
  // k3: sampling + queue mean -> msd bf16
  hipLaunchKernelGGL(k3_sample, dim3(NQ), dim3(256), 0, stream,
                     raw1, refp, vout, msdb);
  // k4: out = msd @ W_out + b_out + query  (40000x256 @ 256x256)
  hipLaunchKernelGGL((mfma_gemm<256, 256, NQ, false, true>), dim3(313, 4), dim3(256), 0, stream,
                     msdb, Wot, b_out, query, out);
}

// Round 3
// 440.658 us; speedup vs baseline: 1.4349x; 1.4021x over previous
//
#include <hip/hip_runtime.h>
#include <math.h>

// Problem constants: EMBED=256, HEADS=8, LEVELS=1, POINTS=4, QUEUE=2, 200x200
#define NQ    40000
#define EMB   256
#define NHEAD 8
#define HDIM  32
#define HB    200
#define WB    200
#define NCOL  192     // 128 off cols + 64 aw cols

typedef __attribute__((ext_vector_type(8))) __bf16 bf16x8;
typedef __attribute__((ext_vector_type(4))) float f32x4;

static __device__ __forceinline__ unsigned short f2bf(float f) {
  unsigned u = __float_as_uint(f);
  u = u + 0x7fffu + ((u >> 16) & 1u);   // round-to-nearest-even
  return (unsigned short)(u >> 16);
}

// ---------------------------------------------------------------------------
// conv_w: transposed bf16 weights + combined bias (tiny, one-shot)
// ---------------------------------------------------------------------------
__global__ __launch_bounds__(256) void conv_w(
    const float* __restrict__ W_off, const float* __restrict__ b_off,
    const float* __restrict__ W_attn, const float* __restrict__ b_attn,
    const float* __restrict__ W_val, const float* __restrict__ W_out,
    unsigned short* __restrict__ Wc1t, unsigned short* __restrict__ Wvt,
    unsigned short* __restrict__ Wot, float* __restrict__ bc1)
{
  int idx = blockIdx.x * 256 + threadIdx.x;
  if (idx < 98304) {                       // Wc1t [192][512]
    int n = idx >> 9, k = idx & 511;
    float v = (n < 128) ? W_off[(size_t)k * 128 + n] : W_attn[(size_t)k * 64 + (n - 128)];
    Wc1t[idx] = f2bf(v);
  } else if (idx < 163840) {               // Wvt [256][256]
    int j = idx - 98304;
    int n = j >> 8, k = j & 255;
    Wvt[j] = f2bf(W_val[(size_t)k * 256 + n]);
  } else if (idx < 229376) {               // Wot [256][256]
    int j = idx - 163840;
    int n = j >> 8, k = j & 255;
    Wot[j] = f2bf(W_out[(size_t)k * 256 + n]);
  } else if (idx < 229568) {               // bc1 [192]
    int n = idx - 229376;
    bc1[n] = (n < 128) ? b_off[n] : b_attn[n - 128];
  }
}

// ---------------------------------------------------------------------------
// MFMA bf16 GEMM: C[M x N] = A[M x K] @ Bt[N x K]^T + bias (+resid)
// BM=128, BN in {64,128}, BK=64; 4 waves (2x2); wave tile 64 x BN/2.
// AMODE: 0 = A bf16 [M][K]; 1 = A fp32 (convert in staging);
//        2 = synth q2: col<256 -> value fp32, else query+query_pos fp32.
// LDS rows padded to 80 ushorts (160 B: 16B-aligned, conflict-minimal).
// ---------------------------------------------------------------------------
template<int K, int N, int BN, int MROWS, int AMODE, bool OUT_BF16, bool RESID>
__global__ __launch_bounds__(256) void mfma_gemm(
    const void* __restrict__ Aptr, const float* __restrict__ Aq,
    const float* __restrict__ Aqp, const unsigned short* __restrict__ Bt,
    const float* __restrict__ bias, const float* __restrict__ resid,
    void* __restrict__ outp)
{
  constexpr int NFN = BN / 32;          // n-frags per wave (2 or 4)
  constexpr int NB  = BN * 8 / 256;     // B staging uint4s per thread
  __shared__ unsigned short As[128][80];
  __shared__ unsigned short Bs[BN][80];
  const int t = threadIdx.x;
  const int m0 = blockIdx.x * 128;
  const int n0 = blockIdx.y * BN;
  const int wid = t >> 6, lane = t & 63;
  const int wm = (wid >> 1) * 64, wn = (wid & 1) * (BN / 2);
  const int lr = lane & 15, quad = lane >> 4;

  f32x4 acc[4][NFN];
  #pragma unroll
  for (int i = 0; i < 4; i++)
    #pragma unroll
    for (int n = 0; n < NFN; n++) acc[i][n] = (f32x4){0.f, 0.f, 0.f, 0.f};

  for (int k0 = 0; k0 < K; k0 += 64) {
    uint4 ra[4]; ushort4 ca[8];
    if constexpr (AMODE == 0) {
      const unsigned short* A = (const unsigned short*)Aptr;
      #pragma unroll
      for (int l = 0; l < 4; l++) {
        int e = t + l * 256, m = e >> 3, c8 = (e & 7) * 8;
        ra[l] = *(const uint4*)(A + (size_t)(m0 + m) * K + k0 + c8);
      }
    } else {
      const float* Av = (const float*)Aptr;
      #pragma unroll
      for (int l = 0; l < 8; l++) {
        int e = t + l * 256, m = e >> 4, c4 = (e & 15) * 4;
        int row = m0 + m;
        if constexpr (MROWS % 128 != 0) row = min(row, MROWS - 1);
        int kk = k0 + c4;
        float4 f;
        if constexpr (AMODE == 1) {
          f = *(const float4*)(Av + (size_t)row * K + kk);
        } else {
          if (kk < 256) {
            f = *(const float4*)(Av + (size_t)row * 256 + kk);
          } else {
            float4 x = *(const float4*)(Aq  + (size_t)row * 256 + (kk - 256));
            float4 y = *(const float4*)(Aqp + (size_t)row * 256 + (kk - 256));
            f = make_float4(x.x + y.x, x.y + y.y, x.z + y.z, x.w + y.w);
          }
        }
        ca[l].x = f2bf(f.x); ca[l].y = f2bf(f.y);
        ca[l].z = f2bf(f.z); ca[l].w = f2bf(f.w);
      }
    }
    uint4 rbv[NB];
    #pragma unroll
    for (int l = 0; l < NB; l++) {
      int e = t + l * 256, n = e >> 3, c8 = (e & 7) * 8;
      rbv[l] = *(const uint4*)(Bt + (size_t)(n0 + n) * K + k0 + c8);
    }
    __syncthreads();
    if constexpr (AMODE == 0) {
      #pragma unroll
      for (int l = 0; l < 4; l++) {
        int e = t + l * 256, m = e >> 3, c8 = (e & 7) * 8;
        *(uint4*)(&As[m][c8]) = ra[l];
      }
    } else {
      #pragma unroll
      for (int l = 0; l < 8; l++) {
        int e = t + l * 256, m = e >> 4, c4 = (e & 15) * 4;
        *(ushort4*)(&As[m][c4]) = ca[l];
      }
    }
    #pragma unroll
    for (int l = 0; l < NB; l++) {
      int e = t + l * 256, n = e >> 3, c8 = (e & 7) * 8;
      *(uint4*)(&Bs[n][c8]) = rbv[l];
    }
    __syncthreads();
    #pragma unroll
    for (int kk = 0; kk < 64; kk += 32) {
      bf16x8 af[4], bfr[NFN];
      #pragma unroll
      for (int i = 0; i < 4; i++)
        af[i] = *(const bf16x8*)(&As[wm + i * 16 + lr][kk + quad * 8]);
      #pragma unroll
      for (int n = 0; n < NFN; n++)
        bfr[n] = *(const bf16x8*)(&Bs[wn + n * 16 + lr][kk + quad * 8]);
      #pragma unroll
      for (int i = 0; i < 4; i++)
        #pragma unroll
        for (int n = 0; n < NFN; n++)
          acc[i][n] = __builtin_amdgcn_mfma_f32_16x16x32_bf16(af[i], bfr[n], acc[i][n], 0, 0, 0);
    }
  }

  // epilogue: C/D layout col=lane&15, row=quad*4+reg
  #pragma unroll
  for (int i = 0; i < 4; i++) {
    int rowb = m0 + wm + i * 16 + quad * 4;
    #pragma unroll
    for (int n = 0; n < NFN; n++) {
      int col = n0 + wn + n * 16 + lr;
      float bsv = bias[col];
      #pragma unroll
      for (int r = 0; r < 4; r++) {
        int rr = rowb + r;
        if ((MROWS % 128 == 0) || rr < MROWS) {
          float v = acc[i][n][r] + bsv;
          if (RESID) v += resid[(size_t)rr * N + col];
          if (OUT_BF16) ((unsigned short*)outp)[(size_t)rr * N + col] = f2bf(v);
          else          ((float*)outp)[(size_t)rr * N + col] = v;
        }
      }
    }
  }
}

// ---------------------------------------------------------------------------
// K3: deformable sampling + queue mean. 2 queries/block.
// Phase 1 (128 thr): per (s,b,h,p) -> 4 corner element-offsets + 4 combined
// weights (bilinear*valid*softmax*0.5) into LDS.
// Phase 2 (256 thr = 2 q x 8 h x 16 d-pairs): 4 uint gathers + 8 FMAs per
// sample; bf16 pair unpack via shl/and.
// ---------------------------------------------------------------------------
__global__ __launch_bounds__(256) void k3_sample(
    const float* __restrict__ raw1, const float* __restrict__ refp,
    const unsigned short* __restrict__ v, unsigned short* __restrict__ msd)
{
  __shared__ int4   sidx[2][64];
  __shared__ float4 swgt[2][64];
  const int t = threadIdx.x;
  const int q0 = blockIdx.x * 2;

  if (t < 128) {
    const int s = t >> 6, e = t & 63;
    const int b = e >> 5, h = (e >> 2) & 7, p = e & 3;
    const int q = q0 + s;
    const float* r = raw1 + (size_t)q * NCOL;
    float ox = r[h * 16 + b * 8 + p * 2 + 0];
    float oy = r[h * 16 + b * 8 + p * 2 + 1];
    float l0 = r[128 + h * 8 + b * 4 + 0];
    float l1 = r[128 + h * 8 + b * 4 + 1];
    float l2 = r[128 + h * 8 + b * 4 + 2];
    float l3 = r[128 + h * 8 + b * 4 + 3];
    float mx = fmaxf(fmaxf(l0, l1), fmaxf(l2, l3));
    float e0 = expf(l0 - mx), e1 = expf(l1 - mx);
    float e2 = expf(l2 - mx), e3 = expf(l3 - mx);
    float ssum = e0 + e1 + e2 + e3;
    float ep = (p == 0) ? e0 : (p == 1) ? e1 : (p == 2) ? e2 : e3;
    float aw = ep / ssum * 0.5f;          // fold queue-mean 0.5 here
    float rx = refp[((size_t)b * NQ + q) * 2 + 0];
    float ry = refp[((size_t)b * NQ + q) * 2 + 1];
    float px = rx * (float)WB + ox - 0.5f;
    float py = ry * (float)HB + oy - 0.5f;
    float x0f = floorf(px), y0f = floorf(py);
    float lx = px - x0f, ly = py - y0f;
    int x0 = (int)x0f, y0 = (int)y0f, x1 = x0 + 1, y1 = y0 + 1;
    int x0c = min(max(x0, 0), WB - 1), x1c = min(max(x1, 0), WB - 1);
    int y0c = min(max(y0, 0), HB - 1), y1c = min(max(y1, 0), HB - 1);
    float vx0 = ((unsigned)x0 < (unsigned)WB) ? 1.f : 0.f;
    float vx1 = ((unsigned)x1 < (unsigned)WB) ? 1.f : 0.f;
    float vy0 = ((unsigned)y0 < (unsigned)HB) ? 1.f : 0.f;
    float vy1 = ((unsigned)y1 < (unsigned)HB) ? 1.f : 0.f;
    const int pb = b * NQ;
    const int hb = h * HDIM;
    int4 ix;
    ix.x = (pb + y0c * WB + x0c) * EMB + hb;
    ix.y = (pb + y0c * WB + x1c) * EMB + hb;
    ix.z = (pb + y1c * WB + x0c) * EMB + hb;
    ix.w = (pb + y1c * WB + x1c) * EMB + hb;
    float4 wv;
    wv.x = aw * (1.f - lx) * (1.f - ly) * vx0 * vy0;
    wv.y = aw * lx * (1.f - ly) * vx1 * vy0;
    wv.z = aw * (1.f - lx) * ly * vx0 * vy1;
    wv.w = aw * lx * ly * vx1 * vy1;
    sidx[s][e] = ix;
    swgt[s][e] = wv;
  }
  __syncthreads();

  const int s = t >> 7, u = t & 127;
  const int h = u >> 4, d2 = u & 15;
  const unsigned short* vd = v + d2 * 2;
  float a0 = 0.f, a1 = 0.f;
  #pragma unroll
  for (int b = 0; b < 2; b++) {
    #pragma unroll
    for (int p = 0; p < 4; p++) {
      int ent = b * 32 + h * 4 + p;
      int4 ix = sidx[s][ent];
      float4 wv = swgt[s][ent];
      unsigned c00 = *(const unsigned*)(vd + ix.x);
      unsigned c10 = *(const unsigned*)(vd + ix.y);
      unsigned c01 = *(const unsigned*)(vd + ix.z);
      unsigned c11 = *(const unsigned*)(vd + ix.w);
      a0 += wv.x * __uint_as_float(c00 << 16);
      a1 += wv.x * __uint_as_float(c00 & 0xffff0000u);
      a0 += wv.y * __uint_as_float(c10 << 16);
      a1 += wv.y * __uint_as_float(c10 & 0xffff0000u);
      a0 += wv.z * __uint_as_float(c01 << 16);
      a1 += wv.z * __uint_as_float(c01 & 0xffff0000u);
      a0 += wv.w * __uint_as_float(c11 << 16);
      a1 += wv.w * __uint_as_float(c11 & 0xffff0000u);
    }
  }
  unsigned pack = ((unsigned)f2bf(a1) << 16) | (unsigned)f2bf(a0);
  *(unsigned*)(msd + (size_t)(q0 + s) * EMB + h * HDIM + d2 * 2) = pack;
}

// ---------------------------------------------------------------------------
extern "C" void kernel_launch(void* const* d_in, const int* in_sizes, int n_in,
                              void* d_out, int out_size, void* d_ws, size_t ws_size,
                              hipStream_t stream) {
  const float* query     = (const float*)d_in[0];
  const float* query_pos = (const float*)d_in[1];
  const float* value     = (const float*)d_in[2];
  const float* refp      = (const float*)d_in[3];
  // d_in[4]: spatial_shapes constant [200,200]
  const float* W_off  = (const float*)d_in[5];
  const float* b_off  = (const float*)d_in[6];
  const float* W_attn = (const float*)d_in[7];
  const float* b_attn = (const float*)d_in[8];
  const float* W_val  = (const float*)d_in[9];
  const float* b_val  = (const float*)d_in[10];
  const float* W_out  = (const float*)d_in[11];
  const float* b_out  = (const float*)d_in[12];
  float* out = (float*)d_out;

  char* ws = (char*)d_ws;
  float*          raw1 = (float*)(ws);                     // 40000*192*4 = 30,720,000
  unsigned short* vout = (unsigned short*)(ws + 30720000); // 80000*256*2 = 40,960,000
  unsigned short* msdb = (unsigned short*)(ws + 71680000); // 40064*256*2 = 20,512,768
  unsigned short* Wc1t = (unsigned short*)(ws + 92192768); // 192*512*2  =    196,608
  unsigned short* Wvt  = (unsigned short*)(ws + 92389376); // 256*256*2  =    131,072
  unsigned short* Wot  = (unsigned short*)(ws + 92520448); // 256*256*2  =    131,072
  float*          bc1  = (float*)(ws + 92651520);          // 192*4

  hipLaunchKernelGGL(conv_w, dim3(897), dim3(256), 0, stream,
                     W_off, b_off, W_attn, b_attn, W_val, W_out, Wc1t, Wvt, Wot, bc1);

  // k1: raw1 = q2 @ [W_off|W_attn] + bc1   (40000x512 @ 512x192), A synthesized
  hipLaunchKernelGGL((mfma_gemm<512, 192, 64, NQ, 2, false, false>),
                     dim3(313, 3), dim3(256), 0, stream,
                     (const void*)value, query, query_pos, Wc1t, bc1,
                     (const float*)nullptr, (void*)raw1);
  // k2: v = value @ W_val + b_val  (80000x256 @ 256x256), fp32 A fused-convert, bf16 out
  hipLaunchKernelGGL((mfma_gemm<256, 256, 128, 80000, 1, true, false>),
                     dim3(625, 2), dim3(256), 0, stream,
                     (const void*)value, (const float*)nullptr, (const float*)nullptr,
                     Wvt, b_val, (const float*)nullptr, (void*)vout);
  // k3: sampling + queue mean -> msd bf16
  hipLaunchKernelGGL(k3_sample, dim3(NQ / 2), dim3(256), 0, stream,
                     raw1, refp, vout, msdb);
  // k4: out = msd @ W_out + b_out + query  (40000x256 @ 256x256)
  hipLaunchKernelGGL((mfma_gemm<256, 256, 128, NQ, 0, false, true>),
                     dim3(313, 2), dim3(256), 0, stream,
                     (const void*)msdb, (const float*)nullptr, (const float*)nullptr,
                     Wot, b_out, query, (void*)out);
}